// Round 2
// baseline (624.827 us; speedup 1.0000x reference)
//
#include <hip/hip_runtime.h>

// VectorQuantizer: x[128,512,64] f32, codebook[1024,64] f32
// outputs (flat in d_out, float32): quantized[4194304], loss[1], indices[65536]
//
// R2: scalar-path screening. The code index v is a thread-invariant loop
// counter -> codebook loads are wave-uniform -> compiler emits s_load into
// SGPRs; inner loop is pure v_fmac_f32 (SGPR x VGPR). No LDS, no barriers.
// fp32 top-2 gap screening + fp64 recheck of rows with gap < TAU keeps the
// argmin fp64-exact. Loss reduced in fp64, fixed order.

static constexpr int Vn    = 1024;
static constexpr int Hn    = 64;
static constexpr int Nrows = 128 * 512;          // 65536
static constexpr int QSZ   = Nrows * Hn;         // 4194304
#define TAU 1e-2f

// ---- ws layout (bytes) ----
// 0      : double cnormd[1024]     (8192)
// 8192   : double partials[4096]   (32768)
// 40960  : float  cnormf[1024]     (4096)
// 45056  : int    bestIdx[65536]   (262144)
// 307200 : int    flagCount        (4, padded to 8)
// 307208 : int    flagList[65536]  (262144)

__global__ void k1_cnorm(const float* __restrict__ cb, double* __restrict__ cnd,
                         float* __restrict__ cnf, int* __restrict__ flagCount) {
  int v = blockIdx.x * blockDim.x + threadIdx.x;
  if (v == 0) *flagCount = 0;
  if (v >= Vn) return;
  const float4* c4 = reinterpret_cast<const float4*>(cb + v * Hn);
  double a0 = 0, a1 = 0, a2 = 0, a3 = 0;
#pragma unroll
  for (int k = 0; k < 16; ++k) {
    float4 f = c4[k];
    a0 += (double)f.x * (double)f.x;
    a1 += (double)f.y * (double)f.y;
    a2 += (double)f.z * (double)f.z;
    a3 += (double)f.w * (double)f.w;
  }
  double s = (a0 + a1) + (a2 + a3);
  cnd[v] = s;
  cnf[v] = (float)s;
}

// Phase 1: 1 row per lane, each thread sweeps all 1024 codes.
// Codebook reads are wave-uniform (v is a loop counter) -> scalar loads.
__global__ __launch_bounds__(256) void k2_phase1(
    const float* __restrict__ x, const float* __restrict__ cb,
    const float* __restrict__ cnf, int* __restrict__ bestIdx,
    int* __restrict__ flagCount, int* __restrict__ flagList,
    float* __restrict__ outIdx) {
  const int row = blockIdx.x * 256 + threadIdx.x;

  float xs[64];
  const float4* xr = reinterpret_cast<const float4*>(x + (long)row * Hn);
#pragma unroll
  for (int k = 0; k < 16; ++k) {
    float4 f = xr[k];
    xs[4 * k + 0] = f.x; xs[4 * k + 1] = f.y;
    xs[4 * k + 2] = f.z; xs[4 * k + 3] = f.w;
  }

  float best = 3.4e38f, best2 = 3.4e38f;
  int bi = 0;

#pragma unroll 2
  for (int v = 0; v < Vn; ++v) {                 // v is uniform across the wave
    const float4* c4 = reinterpret_cast<const float4*>(cb + v * Hn);
    float d0 = 0, d1 = 0, d2 = 0, d3 = 0;
#pragma unroll
    for (int k = 0; k < 16; ++k) {
      float4 f = c4[k];                          // uniform addr -> s_load
      d0 = fmaf(f.x, xs[4 * k + 0], d0);
      d1 = fmaf(f.y, xs[4 * k + 1], d1);
      d2 = fmaf(f.z, xs[4 * k + 2], d2);
      d3 = fmaf(f.w, xs[4 * k + 3], d3);
    }
    float dot = (d0 + d1) + (d2 + d3);
    float key = cnf[v] - 2.0f * dot;
    if (key < best) { best2 = best; best = key; bi = v; }   // strict: first-min
    else            { best2 = fminf(best2, key); }
  }

  bestIdx[row] = bi;
  outIdx[row] = (float)bi;
  if (best2 - best < TAU) {
    int slot = atomicAdd(flagCount, 1);
    flagList[slot] = row;                        // order-independent use
  }
}

// Phase 2: fp64 recheck of flagged rows (all 1024 codes), first-min tie-break.
__global__ __launch_bounds__(256) void k3_recheck(
    const float* __restrict__ x, const float* __restrict__ cb,
    const double* __restrict__ cnd, int* __restrict__ bestIdx,
    const int* __restrict__ flagCount, const int* __restrict__ flagList,
    float* __restrict__ outIdx) {
  __shared__ float xs[64];
  __shared__ double rk[256];
  __shared__ int    ri[256];
  const int tid = threadIdx.x;
  const int cnt = *flagCount;

  for (int jj = blockIdx.x; jj < cnt; jj += gridDim.x) {
    const int row = flagList[jj];
    if (tid < 16)
      reinterpret_cast<float4*>(xs)[tid] =
          reinterpret_cast<const float4*>(x + (long)row * Hn)[tid];
    __syncthreads();

    double bk = 1e300;
    int bi = 0;
#pragma unroll
    for (int cc = 0; cc < 4; ++cc) {
      const int v = cc * 256 + tid;              // ascending per thread
      const float4* c4 = reinterpret_cast<const float4*>(cb + v * Hn);
      double a0 = 0, a1 = 0, a2 = 0, a3 = 0;
#pragma unroll
      for (int k = 0; k < 16; ++k) {
        float4 f = c4[k];
        a0 += (double)f.x * (double)xs[4 * k + 0];
        a1 += (double)f.y * (double)xs[4 * k + 1];
        a2 += (double)f.z * (double)xs[4 * k + 2];
        a3 += (double)f.w * (double)xs[4 * k + 3];
      }
      double dot = (a0 + a1) + (a2 + a3);
      double key = cnd[v] - 2.0 * dot;
      if (key < bk) { bk = key; bi = v; }
    }
    rk[tid] = bk; ri[tid] = bi;
    __syncthreads();
    for (int s = 128; s > 0; s >>= 1) {
      if (tid < s) {
        if (rk[tid + s] < rk[tid] ||
            (rk[tid + s] == rk[tid] && ri[tid + s] < ri[tid])) {
          rk[tid] = rk[tid + s]; ri[tid] = ri[tid + s];
        }
      }
      __syncthreads();
    }
    if (tid == 0) {
      bestIdx[row] = ri[0];
      outIdx[row] = (float)ri[0];
    }
    __syncthreads();
  }
}

// Gather quantized + fp64 per-block loss partials.
__global__ __launch_bounds__(256) void k4_gather(
    const float* __restrict__ x, const float* __restrict__ cb,
    const int* __restrict__ bestIdx, float* __restrict__ out,
    double* __restrict__ partials) {
  __shared__ double red[256];
  const int t = blockIdx.x * 256 + threadIdx.x;  // float4 index
  const int i = t * 4;
  const int row = i >> 6;
  const int h4 = (i & 63) >> 2;
  const int idx = bestIdx[row];
  float4 q  = reinterpret_cast<const float4*>(cb)[idx * 16 + h4];
  float4 xv = reinterpret_cast<const float4*>(x)[t];
  reinterpret_cast<float4*>(out)[t] = q;
  double dx = (double)q.x - (double)xv.x;
  double dy = (double)q.y - (double)xv.y;
  double dz = (double)q.z - (double)xv.z;
  double dw = (double)q.w - (double)xv.w;
  red[threadIdx.x] = dx * dx + dy * dy + dz * dz + dw * dw;
  __syncthreads();
  for (int s = 128; s > 0; s >>= 1) {
    if (threadIdx.x < s) red[threadIdx.x] += red[threadIdx.x + s];
    __syncthreads();
  }
  if (threadIdx.x == 0) partials[blockIdx.x] = red[0];
}

__global__ __launch_bounds__(256) void k6_loss(const double* __restrict__ partials,
                                               float* __restrict__ out) {
  __shared__ double red[256];
  double a = 0;
  for (int k = threadIdx.x; k < 4096; k += 256) a += partials[k];  // fixed order
  red[threadIdx.x] = a;
  __syncthreads();
  for (int s = 128; s > 0; s >>= 1) {
    if (threadIdx.x < s) red[threadIdx.x] += red[threadIdx.x + s];
    __syncthreads();
  }
  if (threadIdx.x == 0)
    out[QSZ] = (float)(1.25 * red[0] / (double)QSZ);
}

extern "C" void kernel_launch(void* const* d_in, const int* in_sizes, int n_in,
                              void* d_out, int out_size, void* d_ws, size_t ws_size,
                              hipStream_t stream) {
  const float* x  = (const float*)d_in[0];
  const float* cb = (const float*)d_in[1];
  float* out = (float*)d_out;
  char* ws = (char*)d_ws;

  double* cnd      = (double*)(ws + 0);
  double* partials = (double*)(ws + 8192);
  float*  cnf      = (float*) (ws + 40960);
  int*    bestIdx  = (int*)   (ws + 45056);
  int*    flagCnt  = (int*)   (ws + 307200);
  int*    flagList = (int*)   (ws + 307208);

  float* outIdx = out + QSZ + 1;

  k1_cnorm  <<<4,    256, 0, stream>>>(cb, cnd, cnf, flagCnt);
  k2_phase1 <<<256,  256, 0, stream>>>(x, cb, cnf, bestIdx, flagCnt, flagList, outIdx);
  k3_recheck<<<128,  256, 0, stream>>>(x, cb, cnd, bestIdx, flagCnt, flagList, outIdx);
  k4_gather <<<4096, 256, 0, stream>>>(x, cb, bestIdx, out, partials);
  k6_loss   <<<1,    256, 0, stream>>>(partials, out);
}

// Round 3
// 217.724 us; speedup vs baseline: 2.8698x; 2.8698x over previous
//
#include <hip/hip_runtime.h>

// VectorQuantizer: x[128,512,64] f32, codebook[1024,64] f32
// outputs (flat in d_out, float32): quantized[4194304], loss[1], indices[65536]
//
// R3: scalar-operand screening with fixed occupancy.
//  - block = 256 thr = 4 waves, owns 64 rows (lane = row); wave w sweeps codes
//    [256w, 256w+256) -> 4096 waves total (16/CU), merged via tiny LDS top-2.
//  - x row pinned in VGPRs via empty asm ("+v") so the compiler cannot sink
//    the loads back into the loop (R2 failure mode: 17 GB L2 traffic).
//  - code index v = 256*readfirstlane(w) + j is provably wave-uniform ->
//    codebook loads take the scalar (s_load) path; FMA = v_fmac(v, s, v).
// fp32 top-2 gap screening + fp64 recheck of rows with gap < TAU keeps the
// argmin fp64-exact. Loss reduced in fp64, fixed order (deterministic).

static constexpr int Vn    = 1024;
static constexpr int Hn    = 64;
static constexpr int Nrows = 128 * 512;          // 65536
static constexpr int QSZ   = Nrows * Hn;         // 4194304
#define TAU 1e-2f

typedef __attribute__((ext_vector_type(4))) float f32x4;

// ---- ws layout (bytes) ----
// 0      : double cnormd[1024]     (8192)
// 8192   : double partials[4096]   (32768)
// 40960  : float  cnormf[1024]     (4096)
// 45056  : int    bestIdx[65536]   (262144)
// 307200 : int    flagCount        (4, padded to 8)
// 307208 : int    flagList[65536]  (262144)

__global__ void k1_cnorm(const float* __restrict__ cb, double* __restrict__ cnd,
                         float* __restrict__ cnf, int* __restrict__ flagCount) {
  int v = blockIdx.x * blockDim.x + threadIdx.x;
  if (v == 0) *flagCount = 0;
  if (v >= Vn) return;
  const float4* c4 = reinterpret_cast<const float4*>(cb + v * Hn);
  double a0 = 0, a1 = 0, a2 = 0, a3 = 0;
#pragma unroll
  for (int k = 0; k < 16; ++k) {
    float4 f = c4[k];
    a0 += (double)f.x * (double)f.x;
    a1 += (double)f.y * (double)f.y;
    a2 += (double)f.z * (double)f.z;
    a3 += (double)f.w * (double)f.w;
  }
  double s = (a0 + a1) + (a2 + a3);
  cnd[v] = s;
  cnf[v] = (float)s;
}

__global__ __launch_bounds__(256, 4) void k2_phase1(
    const float* __restrict__ x, const float* __restrict__ cb,
    const float* __restrict__ cnf, int* __restrict__ bestIdx,
    int* __restrict__ flagCount, int* __restrict__ flagList,
    float* __restrict__ outIdx) {
  __shared__ float sB[4][64];
  __shared__ float sB2[4][64];
  __shared__ int   sI[4][64];

  const int tid  = threadIdx.x;
  const int lane = tid & 63;
  const int w    = __builtin_amdgcn_readfirstlane(tid >> 6);  // wave-uniform
  const int row  = blockIdx.x * 64 + lane;

  // x row -> 16 x f32x4, pinned in VGPRs (asm output can't be rematerialized)
  f32x4 xs[16];
  const f32x4* xr = reinterpret_cast<const f32x4*>(x + (long)row * Hn);
#pragma unroll
  for (int k = 0; k < 16; ++k) xs[k] = xr[k];
#pragma unroll
  for (int k = 0; k < 16; ++k) asm volatile("" : "+v"(xs[k]));

  float best = 3.4e38f, best2 = 3.4e38f;
  int bi = 0;
  const int vbase = w * 256;

  for (int j = 0; j < 256; ++j) {
    const int v = vbase + j;                     // wave-uniform
    const f32x4* c4 = reinterpret_cast<const f32x4*>(cb + v * Hn);
    float d0 = 0, d1 = 0, d2 = 0, d3 = 0;
#pragma unroll
    for (int k = 0; k < 16; ++k) {
      f32x4 f = c4[k];                           // uniform addr -> s_load
      d0 = fmaf(f.x, xs[k].x, d0);
      d1 = fmaf(f.y, xs[k].y, d1);
      d2 = fmaf(f.z, xs[k].z, d2);
      d3 = fmaf(f.w, xs[k].w, d3);
    }
    float dot = (d0 + d1) + (d2 + d3);
    float key = cnf[v] - 2.0f * dot;
    if (key < best) { best2 = best; best = key; bi = v; }   // strict: first-min
    else            { best2 = fminf(best2, key); }
  }

  sB[w][lane] = best; sB2[w][lane] = best2; sI[w][lane] = bi;
  __syncthreads();

  if (w == 0) {
    float B1 = sB[0][lane], B2 = sB2[0][lane];
    int I1 = sI[0][lane];
#pragma unroll
    for (int ww = 1; ww < 4; ++ww) {
      float b = sB[ww][lane], b2 = sB2[ww][lane];
      int i = sI[ww][lane];
      if (b < B1) {                              // ww ascending: ties keep low idx
        B2 = fminf(fminf(B1, b2), B2);
        B1 = b; I1 = i;
      } else {
        B2 = fminf(B2, b);
      }
    }
    bestIdx[row] = I1;
    outIdx[row] = (float)I1;
    if (B2 - B1 < TAU) {
      int slot = atomicAdd(flagCount, 1);
      flagList[slot] = row;                      // order-independent use
    }
  }
}

// Phase 2: fp64 recheck of flagged rows (all 1024 codes), first-min tie-break.
__global__ __launch_bounds__(256) void k3_recheck(
    const float* __restrict__ x, const float* __restrict__ cb,
    const double* __restrict__ cnd, int* __restrict__ bestIdx,
    const int* __restrict__ flagCount, const int* __restrict__ flagList,
    float* __restrict__ outIdx) {
  __shared__ float xs[64];
  __shared__ double rk[256];
  __shared__ int    ri[256];
  const int tid = threadIdx.x;
  const int cnt = *flagCount;

  for (int jj = blockIdx.x; jj < cnt; jj += gridDim.x) {
    const int row = flagList[jj];
    if (tid < 16)
      reinterpret_cast<float4*>(xs)[tid] =
          reinterpret_cast<const float4*>(x + (long)row * Hn)[tid];
    __syncthreads();

    double bk = 1e300;
    int bi = 0;
#pragma unroll
    for (int cc = 0; cc < 4; ++cc) {
      const int v = cc * 256 + tid;              // ascending per thread
      const float4* c4 = reinterpret_cast<const float4*>(cb + v * Hn);
      double a0 = 0, a1 = 0, a2 = 0, a3 = 0;
#pragma unroll
      for (int k = 0; k < 16; ++k) {
        float4 f = c4[k];
        a0 += (double)f.x * (double)xs[4 * k + 0];
        a1 += (double)f.y * (double)xs[4 * k + 1];
        a2 += (double)f.z * (double)xs[4 * k + 2];
        a3 += (double)f.w * (double)xs[4 * k + 3];
      }
      double dot = (a0 + a1) + (a2 + a3);
      double key = cnd[v] - 2.0 * dot;
      if (key < bk) { bk = key; bi = v; }
    }
    rk[tid] = bk; ri[tid] = bi;
    __syncthreads();
    for (int s = 128; s > 0; s >>= 1) {
      if (tid < s) {
        if (rk[tid + s] < rk[tid] ||
            (rk[tid + s] == rk[tid] && ri[tid + s] < ri[tid])) {
          rk[tid] = rk[tid + s]; ri[tid] = ri[tid + s];
        }
      }
      __syncthreads();
    }
    if (tid == 0) {
      bestIdx[row] = ri[0];
      outIdx[row] = (float)ri[0];
    }
    __syncthreads();
  }
}

// Gather quantized + fp64 per-block loss partials.
__global__ __launch_bounds__(256) void k4_gather(
    const float* __restrict__ x, const float* __restrict__ cb,
    const int* __restrict__ bestIdx, float* __restrict__ out,
    double* __restrict__ partials) {
  __shared__ double red[256];
  const int t = blockIdx.x * 256 + threadIdx.x;  // float4 index
  const int i = t * 4;
  const int row = i >> 6;
  const int h4 = (i & 63) >> 2;
  const int idx = bestIdx[row];
  float4 q  = reinterpret_cast<const float4*>(cb)[idx * 16 + h4];
  float4 xv = reinterpret_cast<const float4*>(x)[t];
  reinterpret_cast<float4*>(out)[t] = q;
  double dx = (double)q.x - (double)xv.x;
  double dy = (double)q.y - (double)xv.y;
  double dz = (double)q.z - (double)xv.z;
  double dw = (double)q.w - (double)xv.w;
  red[threadIdx.x] = dx * dx + dy * dy + dz * dz + dw * dw;
  __syncthreads();
  for (int s = 128; s > 0; s >>= 1) {
    if (threadIdx.x < s) red[threadIdx.x] += red[threadIdx.x + s];
    __syncthreads();
  }
  if (threadIdx.x == 0) partials[blockIdx.x] = red[0];
}

__global__ __launch_bounds__(256) void k6_loss(const double* __restrict__ partials,
                                               float* __restrict__ out) {
  __shared__ double red[256];
  double a = 0;
  for (int k = threadIdx.x; k < 4096; k += 256) a += partials[k];  // fixed order
  red[threadIdx.x] = a;
  __syncthreads();
  for (int s = 128; s > 0; s >>= 1) {
    if (threadIdx.x < s) red[threadIdx.x] += red[threadIdx.x + s];
    __syncthreads();
  }
  if (threadIdx.x == 0)
    out[QSZ] = (float)(1.25 * red[0] / (double)QSZ);
}

extern "C" void kernel_launch(void* const* d_in, const int* in_sizes, int n_in,
                              void* d_out, int out_size, void* d_ws, size_t ws_size,
                              hipStream_t stream) {
  const float* x  = (const float*)d_in[0];
  const float* cb = (const float*)d_in[1];
  float* out = (float*)d_out;
  char* ws = (char*)d_ws;

  double* cnd      = (double*)(ws + 0);
  double* partials = (double*)(ws + 8192);
  float*  cnf      = (float*) (ws + 40960);
  int*    bestIdx  = (int*)   (ws + 45056);
  int*    flagCnt  = (int*)   (ws + 307200);
  int*    flagList = (int*)   (ws + 307208);

  float* outIdx = out + QSZ + 1;

  k1_cnorm  <<<4,    256, 0, stream>>>(cb, cnd, cnf, flagCnt);
  k2_phase1 <<<1024, 256, 0, stream>>>(x, cb, cnf, bestIdx, flagCnt, flagList, outIdx);
  k3_recheck<<<128,  256, 0, stream>>>(x, cb, cnd, bestIdx, flagCnt, flagList, outIdx);
  k4_gather <<<4096, 256, 0, stream>>>(x, cb, bestIdx, out, partials);
  k6_loss   <<<1,    256, 0, stream>>>(partials, out);
}